// Round 1
// baseline (190.262 us; speedup 1.0000x reference)
//
#include <hip/hip_runtime.h>

#define TOL_F 1e-5f
#define CLIP_MAX_F 1e5f

// h [8,256,32], e [8,256,256,4], x [8,256,3], q [8,256,1], mask [8,256,256,1]
// W1 [76,32], b1[32], W2 [32,32], b2[32], W3 [32,1], b3[1]  -> out q' [8,256,1]
__global__ __launch_bounds__(256) void epnn_kernel(
    const float* __restrict__ h,
    const float* __restrict__ e,
    const float* __restrict__ x,
    const float* __restrict__ q,
    const float* __restrict__ mask,
    const float* __restrict__ W1,
    const float* __restrict__ b1,
    const float* __restrict__ W2,
    const float* __restrict__ b2,
    const float* __restrict__ W3,
    float* __restrict__ out)
{
    const int N = 256;
    const int b = blockIdx.x >> 8;
    const int i = blockIdx.x & 255;
    const int j = threadIdx.x;

    __shared__ float sAtom[256][37];   // 36 feats + pad (stride 37: conflict-free per-lane reads)
    __shared__ float sW1[76][32];
    __shared__ float sW2T[32][33];     // transposed W2: sW2T[c][k] = W2[k][c]
    __shared__ float sW3[32];
    __shared__ float sB1[32];
    __shared__ float sB2[32];
    __shared__ float sRed[4];

    // ---- stage atom features of batch b: [x(3) | h(32) | q(1)] ----
    {
        const float* xb = x + (b * N + j) * 3;
        sAtom[j][0] = xb[0];
        sAtom[j][1] = xb[1];
        sAtom[j][2] = xb[2];
        const float4* hb = (const float4*)(h + (b * N + j) * 32);
        #pragma unroll
        for (int t = 0; t < 8; ++t) {
            float4 v = hb[t];
            sAtom[j][3 + 4 * t + 0] = v.x;
            sAtom[j][3 + 4 * t + 1] = v.y;
            sAtom[j][3 + 4 * t + 2] = v.z;
            sAtom[j][3 + 4 * t + 3] = v.w;
        }
        sAtom[j][35] = q[b * N + j];
    }
    // ---- stage weights ----
    for (int idx = threadIdx.x; idx < 76 * 32; idx += 256)
        sW1[idx >> 5][idx & 31] = W1[idx];
    for (int idx = threadIdx.x; idx < 32 * 32; idx += 256)
        sW2T[idx & 31][idx >> 5] = W2[idx];
    if (threadIdx.x < 32) {
        sW3[threadIdx.x] = W3[threadIdx.x];
        sB1[threadIdx.x] = b1[threadIdx.x];
        sB2[threadIdx.x] = b2[threadIdx.x];
    }
    __syncthreads();

    // ---- per-edge inputs ----
    const int eoff = (b * N + i) * N + j;
    const float4 ev = ((const float4*)e)[eoff];
    const float m = mask[eoff];
    float c0 = fminf(fmaxf(ev.x, TOL_F), CLIP_MAX_F);
    float c1 = fminf(fmaxf(ev.y, TOL_F), CLIP_MAX_F);
    float c2 = fminf(fmaxf(ev.z, TOL_F), CLIP_MAX_F);
    float c3 = fminf(fmaxf(ev.w, TOL_F), CLIP_MAX_F);
    float largest = fmaxf(fmaxf(c0, c1), fmaxf(c2, c3));
    const float nearf = (largest != TOL_F) ? 1.0f : 0.0f;

    // ---- layer 1: two MLPs share every weight read ----
    // z_a = [ai | aj | e], z_b = [aj | ai | e]
    float h1a[32], h1b[32];
    #pragma unroll
    for (int c = 0; c < 32; ++c) { h1a[c] = sB1[c]; h1b[c] = sB1[c]; }

    #pragma unroll 4
    for (int k = 0; k < 36; ++k) {
        const float ai = sAtom[i][k];   // uniform -> LDS broadcast
        const float aj = sAtom[j][k];   // per-lane, stride-37 conflict-free
        #pragma unroll
        for (int c = 0; c < 32; ++c) {
            const float wlo = sW1[k][c];        // uniform broadcasts, b128-vectorizable
            const float whi = sW1[36 + k][c];
            h1a[c] = fmaf(ai, wlo, h1a[c]);
            h1a[c] = fmaf(aj, whi, h1a[c]);
            h1b[c] = fmaf(aj, wlo, h1b[c]);
            h1b[c] = fmaf(ai, whi, h1b[c]);
        }
    }
    {
        const float ez[4] = {ev.x, ev.y, ev.z, ev.w};
        #pragma unroll
        for (int k = 0; k < 4; ++k) {
            const float z = ez[k];
            #pragma unroll
            for (int c = 0; c < 32; ++c) {
                const float w = sW1[72 + k][c];
                h1a[c] = fmaf(z, w, h1a[c]);
                h1b[c] = fmaf(z, w, h1b[c]);
            }
        }
    }
    #pragma unroll
    for (int c = 0; c < 32; ++c) {
        h1a[c] = fmaxf(h1a[c], 0.0f);
        h1b[c] = fmaxf(h1b[c], 0.0f);
    }

    // ---- layers 2+3 fused (c-outer): avoids h2 register arrays ----
    float outa = 0.0f, outb = 0.0f;
    #pragma unroll 4
    for (int c = 0; c < 32; ++c) {
        float acca = sB2[c], accb = sB2[c];
        #pragma unroll
        for (int k = 0; k < 32; ++k) {
            const float w = sW2T[c][k];
            acca = fmaf(h1a[k], w, acca);
            accb = fmaf(h1b[k], w, accb);
        }
        const float w3 = sW3[c];
        outa = fmaf(fmaxf(acca, 0.0f), w3, outa);
        outb = fmaf(fmaxf(accb, 0.0f), w3, outb);
    }
    // b3 cancels in (outa+b3)-(outb+b3)

    float d = 0.5f * (outa - outb) * m * nearf;

    // ---- block reduction over j ----
    #pragma unroll
    for (int off = 32; off > 0; off >>= 1)
        d += __shfl_down(d, off, 64);
    const int lane = threadIdx.x & 63;
    const int wid = threadIdx.x >> 6;
    if (lane == 0) sRed[wid] = d;
    __syncthreads();
    if (threadIdx.x == 0) {
        const float s = sRed[0] + sRed[1] + sRed[2] + sRed[3];
        out[b * N + i] = q[b * N + i] + s;
    }
}

extern "C" void kernel_launch(void* const* d_in, const int* in_sizes, int n_in,
                              void* d_out, int out_size, void* d_ws, size_t ws_size,
                              hipStream_t stream) {
    const float* h    = (const float*)d_in[0];
    const float* e    = (const float*)d_in[1];
    const float* x    = (const float*)d_in[2];
    const float* q    = (const float*)d_in[3];
    const float* mask = (const float*)d_in[4];
    const float* W1   = (const float*)d_in[5];
    const float* b1   = (const float*)d_in[6];
    const float* W2   = (const float*)d_in[7];
    const float* b2   = (const float*)d_in[8];
    const float* W3   = (const float*)d_in[9];
    float* out = (float*)d_out;

    dim3 grid(8 * 256);
    dim3 block(256);
    hipLaunchKernelGGL(epnn_kernel, grid, block, 0, stream,
                       h, e, x, q, mask, W1, b1, W2, b2, W3, out);
}

// Round 2
// 120.717 us; speedup vs baseline: 1.5761x; 1.5761x over previous
//
#include <hip/hip_runtime.h>

#define TOL_F 1e-5f
#define CLIP_MAX_F 1e5f

// Inputs: h [8,256,32], e [8,256,256,4], x [8,256,3], q [8,256,1],
//         mask [8,256,256,1], W1 [76,32], b1[32], W2 [32,32], b2[32],
//         W3 [32,1], b3[1]  -> out q' [8,256,1]
//
// Factorization: layer-1 preactivation is linear:
//   z_ij @ W1 = atom_i @ W1[0:36] + atom_j @ W1[36:72] + e_ij @ W1[72:76]
// Per-atom parts (Alo, Ahi) precomputed once into d_ws as
//   AT[b][cc][n]  (cc 0..31 = Alo, 32..63 = Ahi), transposed for coalescing.

__global__ __launch_bounds__(256) void precompute_kernel(
    const float* __restrict__ h,
    const float* __restrict__ x,
    const float* __restrict__ q,
    const float* __restrict__ W1,
    float* __restrict__ AT)
{
    const int gid = blockIdx.x * 256 + threadIdx.x;   // 0 .. 131071
    const int n  = gid >> 6;                          // global atom 0..2047
    const int cc = gid & 63;                          // output channel (lo/hi)
    const int b  = n >> 8;
    const int nl = n & 255;
    const int c  = cc & 31;
    const int rowbase = (cc < 32) ? 0 : 36;
    const float* Wcol = W1 + rowbase * 32 + c;        // Wcol[k*32] = W1[rowbase+k][c]

    const float* xp = x + n * 3;
    float acc = xp[0] * Wcol[0];
    acc = fmaf(xp[1], Wcol[32], acc);
    acc = fmaf(xp[2], Wcol[64], acc);
    const float* hp = h + n * 32;
    #pragma unroll
    for (int k = 0; k < 32; ++k)
        acc = fmaf(hp[k], Wcol[(3 + k) * 32], acc);
    acc = fmaf(q[n], Wcol[35 * 32], acc);

    AT[(b * 64 + cc) * 256 + nl] = acc;
}

__global__ __launch_bounds__(256) void edge_kernel(
    const float* __restrict__ e,
    const float* __restrict__ q,
    const float* __restrict__ mask,
    const float* __restrict__ W1,
    const float* __restrict__ b1,
    const float* __restrict__ W2,
    const float* __restrict__ b2,
    const float* __restrict__ W3,
    const float* __restrict__ AT,
    float* __restrict__ out)
{
    const int N = 256;
    const int b = blockIdx.x >> 8;
    const int i = blockIdx.x & 255;
    const int j = threadIdx.x;

    __shared__ float sW2T[32][33];   // sW2T[c][k] = W2[k][c]
    __shared__ float sWe[4][32];     // W1 rows 72..75
    __shared__ float sB1[32];
    __shared__ float sB2[32];
    __shared__ float sW3[32];
    __shared__ float sAI[64];        // Alo[i] (0..31) | Ahi[i] (32..63), uniform
    __shared__ float sRed[4];

    for (int idx = threadIdx.x; idx < 32 * 32; idx += 256)
        sW2T[idx & 31][idx >> 5] = W2[idx];
    if (threadIdx.x < 128)
        sWe[threadIdx.x >> 5][threadIdx.x & 31] = W1[72 * 32 + threadIdx.x];
    if (threadIdx.x < 32) {
        sB1[threadIdx.x] = b1[threadIdx.x];
        sB2[threadIdx.x] = b2[threadIdx.x];
        sW3[threadIdx.x] = W3[threadIdx.x];
    }
    if (threadIdx.x < 64)
        sAI[threadIdx.x] = AT[(b * 64 + threadIdx.x) * 256 + i];
    __syncthreads();

    // ---- per-edge inputs ----
    const int eoff = (b * N + i) * N + j;
    const float4 ev = ((const float4*)e)[eoff];
    const float m = mask[eoff];
    float c0 = fminf(fmaxf(ev.x, TOL_F), CLIP_MAX_F);
    float c1 = fminf(fmaxf(ev.y, TOL_F), CLIP_MAX_F);
    float c2 = fminf(fmaxf(ev.z, TOL_F), CLIP_MAX_F);
    float c3 = fminf(fmaxf(ev.w, TOL_F), CLIP_MAX_F);
    const float largest = fmaxf(fmaxf(c0, c1), fmaxf(c2, c3));
    const float nearf = (largest != TOL_F) ? 1.0f : 0.0f;

    // ---- layer 1 via precomputed atom parts ----
    const float* Ab = AT + b * 64 * 256 + j;   // Ab[cc*256] = AT[b][cc][j]
    float h1a[32], h1b[32];
    #pragma unroll
    for (int c = 0; c < 32; ++c) {
        float ew = sB1[c];
        ew = fmaf(ev.x, sWe[0][c], ew);
        ew = fmaf(ev.y, sWe[1][c], ew);
        ew = fmaf(ev.z, sWe[2][c], ew);
        ew = fmaf(ev.w, sWe[3][c], ew);
        const float alj = Ab[c * 256];          // Alo[j][c]  (coalesced)
        const float ahj = Ab[(32 + c) * 256];   // Ahi[j][c]
        h1a[c] = fmaxf(sAI[c] + ahj + ew, 0.0f);        // [ai|aj|e]
        h1b[c] = fmaxf(alj + sAI[32 + c] + ew, 0.0f);   // [aj|ai|e]
    }

    // ---- layers 2+3 fused ----
    float outa = 0.0f, outb = 0.0f;
    #pragma unroll 4
    for (int c = 0; c < 32; ++c) {
        float acca = sB2[c], accb = sB2[c];
        #pragma unroll
        for (int k = 0; k < 32; ++k) {
            const float w = sW2T[c][k];
            acca = fmaf(h1a[k], w, acca);
            accb = fmaf(h1b[k], w, accb);
        }
        const float w3 = sW3[c];
        outa = fmaf(fmaxf(acca, 0.0f), w3, outa);
        outb = fmaf(fmaxf(accb, 0.0f), w3, outb);
    }
    // b3 cancels in the antisymmetric difference

    float d = 0.5f * (outa - outb) * m * nearf;

    // ---- block reduction over j ----
    #pragma unroll
    for (int off = 32; off > 0; off >>= 1)
        d += __shfl_down(d, off, 64);
    const int lane = threadIdx.x & 63;
    const int wid = threadIdx.x >> 6;
    if (lane == 0) sRed[wid] = d;
    __syncthreads();
    if (threadIdx.x == 0) {
        const float s = sRed[0] + sRed[1] + sRed[2] + sRed[3];
        out[b * N + i] = q[b * N + i] + s;
    }
}

extern "C" void kernel_launch(void* const* d_in, const int* in_sizes, int n_in,
                              void* d_out, int out_size, void* d_ws, size_t ws_size,
                              hipStream_t stream) {
    const float* h    = (const float*)d_in[0];
    const float* e    = (const float*)d_in[1];
    const float* x    = (const float*)d_in[2];
    const float* q    = (const float*)d_in[3];
    const float* mask = (const float*)d_in[4];
    const float* W1   = (const float*)d_in[5];
    const float* b1   = (const float*)d_in[6];
    const float* W2   = (const float*)d_in[7];
    const float* b2   = (const float*)d_in[8];
    const float* W3   = (const float*)d_in[9];
    float* out = (float*)d_out;
    float* AT  = (float*)d_ws;   // 8*64*256 floats = 512 KB

    hipLaunchKernelGGL(precompute_kernel, dim3(512), dim3(256), 0, stream,
                       h, x, q, W1, AT);
    hipLaunchKernelGGL(edge_kernel, dim3(8 * 256), dim3(256), 0, stream,
                       e, q, mask, W1, b1, W2, b2, W3, AT, out);
}

// Round 4
// 103.562 us; speedup vs baseline: 1.8372x; 1.1656x over previous
//
#include <hip/hip_runtime.h>
#include <hip/hip_bf16.h>

#define TOL_F 1e-5f
#define CLIP_MAX_F 1e5f

typedef __attribute__((ext_vector_type(8))) short v8s;   // 8 bf16 (A/B frag)
typedef __attribute__((ext_vector_type(4))) float v4f;   // 4 f32  (C/D frag)

__device__ inline unsigned short f2bf(float f) {
    __hip_bfloat16 t = __float2bfloat16(f);
    union { __hip_bfloat16 b; unsigned short u; } cv;
    cv.b = t;
    return cv.u;
}

// Per-atom factorization of layer 1 (linear before ReLU):
//   z_ij @ W1 = Alo[i] + Ahi[j] + e_ij @ We   (+ b1)
// AT[n][cc]: cc 0..31 = Alo[n][c] (rows 0..35 of W1), cc 32..63 = Ahi[n][c] (rows 36..71).
__global__ __launch_bounds__(256) void precompute_kernel(
    const float* __restrict__ h,
    const float* __restrict__ x,
    const float* __restrict__ q,
    const float* __restrict__ W1,
    float* __restrict__ AT)
{
    const int gid = blockIdx.x * 256 + threadIdx.x;   // 0 .. 131071
    const int n  = gid >> 6;                          // atom 0..2047 (uniform per wave)
    const int cc = gid & 63;
    const int c  = cc & 31;
    const int rowbase = (cc < 32) ? 0 : 36;
    const float* Wcol = W1 + rowbase * 32 + c;

    const float* xp = x + n * 3;
    float acc = xp[0] * Wcol[0];
    acc = fmaf(xp[1], Wcol[32], acc);
    acc = fmaf(xp[2], Wcol[64], acc);
    const float* hp = h + n * 32;
    #pragma unroll
    for (int k = 0; k < 32; ++k)
        acc = fmaf(hp[k], Wcol[(3 + k) * 32], acc);
    acc = fmaf(q[n], Wcol[35 * 32], acc);

    AT[n * 64 + cc] = acc;                            // atom-major, coalesced
}

// Block (b,i): computes elec(i,j) and elec(j,i) for all j via MFMA layer-2,
// reduces the antisymmetric masked sum in-block. W2 lives in registers as
// B-fragments the whole kernel; no LDS in the hot loop.
__global__ __launch_bounds__(256) void edge_kernel(
    const float* __restrict__ e,
    const float* __restrict__ q,
    const float* __restrict__ mask,
    const float* __restrict__ W1,
    const float* __restrict__ b1,
    const float* __restrict__ W2,
    const float* __restrict__ b2,
    const float* __restrict__ W3,
    const float* __restrict__ AT,
    float* __restrict__ out)
{
    const int b = blockIdx.x >> 8;
    const int i = blockIdx.x & 255;
    const int lane = threadIdx.x & 63;
    const int wv = threadIdx.x >> 6;
    const int oc = lane & 15;        // A row (edge-in-tile) / B,D col (out channel)
    const int kg = lane >> 4;        // k-octet group
    const int c0 = kg * 8;           // k (= hidden channel) base for A/B frags

    // ---- W2 B-fragments in registers: B[k][col], k = c0..c0+7, col = oc / oc+16 ----
    v8s B0, B1;
    {
        union { unsigned short u[8]; v8s v; } ub0, ub1;
        #pragma unroll
        for (int jj = 0; jj < 8; ++jj) {
            ub0.u[jj] = f2bf(W2[(c0 + jj) * 32 + oc]);
            ub1.u[jj] = f2bf(W2[(c0 + jj) * 32 + oc + 16]);
        }
        B0 = ub0.v; B1 = ub1.v;
    }
    const float b2a = b2[oc], b2b = b2[oc + 16];
    const float w3a = W3[oc], w3b = W3[oc + 16];

    // ---- per-lane uniforms: base vectors (i-side parts + b1) and We ----
    const float* ATi = AT + (b * 256 + i) * 64;
    float base_a[8], base_b[8];     // a: [atom_i|atom_j]: Alo[i]+b1 ; b: [atom_j|atom_i]: Ahi[i]+b1
    float We[4][8];                 // W1 rows 72..75, cols c0..c0+7
    #pragma unroll
    for (int jj = 0; jj < 8; ++jj) {
        const float bb = b1[c0 + jj];
        base_a[jj] = ATi[c0 + jj] + bb;
        base_b[jj] = ATi[32 + c0 + jj] + bb;
        #pragma unroll
        for (int t = 0; t < 4; ++t)
            We[t][jj] = W1[(72 + t) * 32 + c0 + jj];
    }

    const v4f Z = {0.f, 0.f, 0.f, 0.f};
    float qacc = 0.f;

    #pragma unroll
    for (int t = 0; t < 4; ++t) {
        const int jE = wv * 64 + t * 16 + oc;                 // this lane's edge (A row)
        const int eoff = (b * 256 + i) * 256 + jE;

        const float4 ev = ((const float4*)e)[eoff];
        const float m = mask[eoff];
        const float cl0 = fminf(fmaxf(ev.x, TOL_F), CLIP_MAX_F);
        const float cl1 = fminf(fmaxf(ev.y, TOL_F), CLIP_MAX_F);
        const float cl2 = fminf(fmaxf(ev.z, TOL_F), CLIP_MAX_F);
        const float cl3 = fminf(fmaxf(ev.w, TOL_F), CLIP_MAX_F);
        const float largest = fmaxf(fmaxf(cl0, cl1), fmaxf(cl2, cl3));
        const float nearf = (largest != TOL_F) ? 1.0f : 0.0f;
        const float scale = 0.5f * m * nearf;

        // ---- layer 1 for this lane's A-frag slice: edge jE, channels c0..c0+7 ----
        const float4* ATj4 = (const float4*)(AT + (b * 256 + jE) * 64);
        const float4 lo0 = ATj4[kg * 2],     lo1 = ATj4[kg * 2 + 1];   // Alo[j] octet
        const float4 hi0 = ATj4[8 + kg * 2], hi1 = ATj4[9 + kg * 2];   // Ahi[j] octet
        const float alo[8] = {lo0.x, lo0.y, lo0.z, lo0.w, lo1.x, lo1.y, lo1.z, lo1.w};
        const float ahi[8] = {hi0.x, hi0.y, hi0.z, hi0.w, hi1.x, hi1.y, hi1.z, hi1.w};

        union { unsigned short u[8]; v8s v; } ua, ub;
        #pragma unroll
        for (int jj = 0; jj < 8; ++jj) {
            float ew = We[0][jj] * ev.x;
            ew = fmaf(We[1][jj], ev.y, ew);
            ew = fmaf(We[2][jj], ev.z, ew);
            ew = fmaf(We[3][jj], ev.w, ew);
            const float pa = base_a[jj] + ahi[jj] + ew;   // [atom_i|atom_j|e]
            const float pb = base_b[jj] + alo[jj] + ew;   // [atom_j|atom_i|e]
            ua.u[jj] = f2bf(fmaxf(pa, 0.f));
            ub.u[jj] = f2bf(fmaxf(pb, 0.f));
        }

        // ---- layer 2 via MFMA: D[row=edge][col=out-ch] ----
        v4f Da0 = __builtin_amdgcn_mfma_f32_16x16x32_bf16(ua.v, B0, Z, 0, 0, 0);
        v4f Da1 = __builtin_amdgcn_mfma_f32_16x16x32_bf16(ua.v, B1, Z, 0, 0, 0);
        v4f Db0 = __builtin_amdgcn_mfma_f32_16x16x32_bf16(ub.v, B0, Z, 0, 0, 0);
        v4f Db1 = __builtin_amdgcn_mfma_f32_16x16x32_bf16(ub.v, B1, Z, 0, 0, 0);

        // ---- layer 3 + antisym + masked accumulate ----
        // D mapping: col = lane&15 = oc, row (edge-in-tile) = kg*4 + r.
        #pragma unroll
        for (int r = 0; r < 4; ++r) {
            float va = fmaxf(Da1[r] + b2b, 0.f) * w3b;
            va = fmaf(fmaxf(Da0[r] + b2a, 0.f), w3a, va);
            float vb = fmaxf(Db1[r] + b2b, 0.f) * w3b;
            vb = fmaf(fmaxf(Db0[r] + b2a, 0.f), w3a, vb);
            const float sc = __shfl(scale, kg * 4 + r, 64);  // scale lives on lanes 0..15
            qacc += (va - vb) * sc;                          // b3 cancels in va-vb
        }
    }

    // ---- block reduction ----
    #pragma unroll
    for (int off = 32; off > 0; off >>= 1)
        qacc += __shfl_down(qacc, off, 64);
    __shared__ float sRed[4];
    if (lane == 0) sRed[wv] = qacc;
    __syncthreads();
    if (threadIdx.x == 0) {
        out[b * 256 + i] = q[b * 256 + i] + (sRed[0] + sRed[1] + sRed[2] + sRed[3]);
    }
}

extern "C" void kernel_launch(void* const* d_in, const int* in_sizes, int n_in,
                              void* d_out, int out_size, void* d_ws, size_t ws_size,
                              hipStream_t stream) {
    const float* h    = (const float*)d_in[0];
    const float* e    = (const float*)d_in[1];
    const float* x    = (const float*)d_in[2];
    const float* q    = (const float*)d_in[3];
    const float* mask = (const float*)d_in[4];
    const float* W1   = (const float*)d_in[5];
    const float* b1   = (const float*)d_in[6];
    const float* W2   = (const float*)d_in[7];
    const float* b2   = (const float*)d_in[8];
    const float* W3   = (const float*)d_in[9];
    float* out = (float*)d_out;
    float* AT  = (float*)d_ws;   // 2048*64 floats = 512 KB

    hipLaunchKernelGGL(precompute_kernel, dim3(512), dim3(256), 0, stream,
                       h, x, q, W1, AT);
    hipLaunchKernelGGL(edge_kernel, dim3(8 * 256), dim3(256), 0, stream,
                       e, q, mask, W1, b1, W2, b2, W3, AT, out);
}

// Round 5
// 97.622 us; speedup vs baseline: 1.9490x; 1.0608x over previous
//
#include <hip/hip_runtime.h>
#include <hip/hip_bf16.h>

#define TOL_F 1e-5f
#define CLIP_MAX_F 1e5f

typedef __attribute__((ext_vector_type(8))) short v8s;   // 8 bf16 (A/B frag)
typedef __attribute__((ext_vector_type(4))) float v4f;   // 4 f32  (C/D frag)

__device__ inline unsigned short f2bf(float f) {
    __hip_bfloat16 t = __float2bfloat16(f);
    union { __hip_bfloat16 b; unsigned short u; } cv;
    cv.b = t;
    return cv.u;
}

// Per-atom factorization of layer 1 (linear before ReLU):
//   z_ij @ W1 = Alo[i] + Ahi[j] + e_ij @ We   (+ b1)
// AT[n][cc]: cc 0..31 = Alo[n][c] (W1 rows 0..35), cc 32..63 = Ahi[n][c] (rows 36..71).
__global__ __launch_bounds__(256) void precompute_kernel(
    const float* __restrict__ h,
    const float* __restrict__ x,
    const float* __restrict__ q,
    const float* __restrict__ W1,
    float* __restrict__ AT)
{
    const int gid = blockIdx.x * 256 + threadIdx.x;   // 0 .. 131071
    const int n  = gid >> 6;                          // atom 0..2047
    const int cc = gid & 63;
    const int c  = cc & 31;
    const int rowbase = (cc < 32) ? 0 : 36;
    const float* Wcol = W1 + rowbase * 32 + c;

    const float* xp = x + n * 3;
    float acc = xp[0] * Wcol[0];
    acc = fmaf(xp[1], Wcol[32], acc);
    acc = fmaf(xp[2], Wcol[64], acc);
    const float* hp = h + n * 32;
    #pragma unroll
    for (int k = 0; k < 32; ++k)
        acc = fmaf(hp[k], Wcol[(3 + k) * 32], acc);
    acc = fmaf(q[n], Wcol[35 * 32], acc);

    AT[n * 64 + cc] = acc;                            // atom-major, coalesced
}

// Block (b, i-pair): two i-rows share all AT[j] gathers and the in-register
// W2 B-fragments. Layer 2 via MFMA; layer 3 deferred past the j-loop
// (linear after the per-column scaled-ReLU accumulation).
__global__ __launch_bounds__(256) void edge_kernel(
    const float* __restrict__ e,
    const float* __restrict__ q,
    const float* __restrict__ mask,
    const float* __restrict__ W1,
    const float* __restrict__ b1,
    const float* __restrict__ W2,
    const float* __restrict__ b2,
    const float* __restrict__ W3,
    const float* __restrict__ AT,
    float* __restrict__ out)
{
    const int b  = blockIdx.x >> 7;          // batch
    const int i0 = (blockIdx.x & 127) * 2;   // first of two i-rows
    const int i1 = i0 + 1;
    const int lane = threadIdx.x & 63;
    const int wv = threadIdx.x >> 6;
    const int oc = lane & 15;        // A row (edge) / B,D col (out channel)
    const int kg = lane >> 4;        // k-octet group
    const int c0 = kg * 8;           // hidden-channel base for A/B frags

    // ---- W2 B-fragments in registers: B[k][col], k = c0..c0+7 ----
    v8s B0, B1;
    {
        union { unsigned short u[8]; v8s v; } ub0, ub1;
        #pragma unroll
        for (int jj = 0; jj < 8; ++jj) {
            ub0.u[jj] = f2bf(W2[(c0 + jj) * 32 + oc]);
            ub1.u[jj] = f2bf(W2[(c0 + jj) * 32 + oc + 16]);
        }
        B0 = ub0.v; B1 = ub1.v;
    }
    const float b2a = b2[oc], b2b = b2[oc + 16];

    // ---- per-lane uniforms: i-side bases (+b1) for both rows, and We ----
    const float* ATi0 = AT + (b * 256 + i0) * 64;
    const float* ATi1 = AT + (b * 256 + i1) * 64;
    float ba0[8], bb0[8], ba1[8], bb1[8];
    float We[4][8];                  // W1 rows 72..75, cols c0..c0+7
    #pragma unroll
    for (int jj = 0; jj < 8; ++jj) {
        const float bb = b1[c0 + jj];
        ba0[jj] = ATi0[c0 + jj] + bb;
        bb0[jj] = ATi0[32 + c0 + jj] + bb;
        ba1[jj] = ATi1[c0 + jj] + bb;
        bb1[jj] = ATi1[32 + c0 + jj] + bb;
        #pragma unroll
        for (int t = 0; t < 4; ++t)
            We[t][jj] = W1[(72 + t) * 32 + c0 + jj];
    }

    const v4f Z = {0.f, 0.f, 0.f, 0.f};
    float accA0 = 0.f, accB0 = 0.f, accA1 = 0.f, accB1 = 0.f;

    #pragma unroll
    for (int t = 0; t < 4; ++t) {
        const int jE = wv * 64 + t * 16 + oc;            // this lane's edge row
        const int eoff = (b * 256 + i0) * 256 + jE;

        // ---- loads first (both rows + shared AT quads) ----
        const float4 ev0 = ((const float4*)e)[eoff];
        const float4 ev1 = ((const float4*)e)[eoff + 256];
        const float m0 = mask[eoff];
        const float m1 = mask[eoff + 256];
        const float4* ATj4 = (const float4*)(AT + (b * 256 + jE) * 64);
        const float4 lo0 = ATj4[kg * 2],     lo1 = ATj4[kg * 2 + 1];
        const float4 hi0 = ATj4[8 + kg * 2], hi1 = ATj4[9 + kg * 2];
        const float alo[8] = {lo0.x, lo0.y, lo0.z, lo0.w, lo1.x, lo1.y, lo1.z, lo1.w};
        const float ahi[8] = {hi0.x, hi0.y, hi0.z, hi0.w, hi1.x, hi1.y, hi1.z, hi1.w};

        // ---- per-edge scale (mask * is_near), 0.5 deferred to epilogue ----
        float cl0 = fminf(fmaxf(ev0.x, TOL_F), CLIP_MAX_F);
        float cl1 = fminf(fmaxf(ev0.y, TOL_F), CLIP_MAX_F);
        float cl2 = fminf(fmaxf(ev0.z, TOL_F), CLIP_MAX_F);
        float cl3 = fminf(fmaxf(ev0.w, TOL_F), CLIP_MAX_F);
        float lg0 = fmaxf(fmaxf(cl0, cl1), fmaxf(cl2, cl3));
        const float scale0 = (lg0 != TOL_F) ? m0 : 0.0f;
        cl0 = fminf(fmaxf(ev1.x, TOL_F), CLIP_MAX_F);
        cl1 = fminf(fmaxf(ev1.y, TOL_F), CLIP_MAX_F);
        cl2 = fminf(fmaxf(ev1.z, TOL_F), CLIP_MAX_F);
        cl3 = fminf(fmaxf(ev1.w, TOL_F), CLIP_MAX_F);
        float lg1 = fmaxf(fmaxf(cl0, cl1), fmaxf(cl2, cl3));
        const float scale1 = (lg1 != TOL_F) ? m1 : 0.0f;

        // ---- layer 1 for both rows (We/base in regs, AT quads shared) ----
        union { unsigned short u[8]; v8s v; } ua0, ub0v, ua1, ub1v;
        #pragma unroll
        for (int jj = 0; jj < 8; ++jj) {
            float ew0 = We[0][jj] * ev0.x;
            ew0 = fmaf(We[1][jj], ev0.y, ew0);
            ew0 = fmaf(We[2][jj], ev0.z, ew0);
            ew0 = fmaf(We[3][jj], ev0.w, ew0);
            float ew1 = We[0][jj] * ev1.x;
            ew1 = fmaf(We[1][jj], ev1.y, ew1);
            ew1 = fmaf(We[2][jj], ev1.z, ew1);
            ew1 = fmaf(We[3][jj], ev1.w, ew1);
            ua0.u[jj]  = f2bf(fmaxf(ba0[jj] + ahi[jj] + ew0, 0.f));  // [i0|j|e]
            ub0v.u[jj] = f2bf(fmaxf(bb0[jj] + alo[jj] + ew0, 0.f));  // [j|i0|e]
            ua1.u[jj]  = f2bf(fmaxf(ba1[jj] + ahi[jj] + ew1, 0.f));  // [i1|j|e]
            ub1v.u[jj] = f2bf(fmaxf(bb1[jj] + alo[jj] + ew1, 0.f));  // [j|i1|e]
        }

        // ---- layer 2 via MFMA ----
        v4f Da00 = __builtin_amdgcn_mfma_f32_16x16x32_bf16(ua0.v,  B0, Z, 0, 0, 0);
        v4f Da01 = __builtin_amdgcn_mfma_f32_16x16x32_bf16(ua0.v,  B1, Z, 0, 0, 0);
        v4f Db00 = __builtin_amdgcn_mfma_f32_16x16x32_bf16(ub0v.v, B0, Z, 0, 0, 0);
        v4f Db01 = __builtin_amdgcn_mfma_f32_16x16x32_bf16(ub0v.v, B1, Z, 0, 0, 0);
        v4f Da10 = __builtin_amdgcn_mfma_f32_16x16x32_bf16(ua1.v,  B0, Z, 0, 0, 0);
        v4f Da11 = __builtin_amdgcn_mfma_f32_16x16x32_bf16(ua1.v,  B1, Z, 0, 0, 0);
        v4f Db10 = __builtin_amdgcn_mfma_f32_16x16x32_bf16(ub1v.v, B0, Z, 0, 0, 0);
        v4f Db11 = __builtin_amdgcn_mfma_f32_16x16x32_bf16(ub1v.v, B1, Z, 0, 0, 0);

        // ---- scaled antisym ReLU accumulation per column ----
        // D mapping: col = oc, row (edge-in-tile) = kg*4 + r; scales on lanes 0..15.
        #pragma unroll
        for (int r = 0; r < 4; ++r) {
            const float sc0 = __shfl(scale0, kg * 4 + r, 64);
            const float sc1 = __shfl(scale1, kg * 4 + r, 64);
            accA0 += sc0 * (fmaxf(Da00[r] + b2a, 0.f) - fmaxf(Db00[r] + b2a, 0.f));
            accB0 += sc0 * (fmaxf(Da01[r] + b2b, 0.f) - fmaxf(Db01[r] + b2b, 0.f));
            accA1 += sc1 * (fmaxf(Da10[r] + b2a, 0.f) - fmaxf(Db10[r] + b2a, 0.f));
            accB1 += sc1 * (fmaxf(Da11[r] + b2b, 0.f) - fmaxf(Db11[r] + b2b, 0.f));
        }
    }

    // ---- deferred layer 3 (linear): val = 0.5 * (accA*W3[oc] + accB*W3[oc+16]) ----
    const float w3a = W3[oc], w3b = W3[oc + 16];
    float v0 = 0.5f * (accA0 * w3a + accB0 * w3b);
    float v1 = 0.5f * (accA1 * w3a + accB1 * w3b);

    // ---- reductions (sum over all lanes = sum over cols, rows, t, waves) ----
    #pragma unroll
    for (int off = 32; off > 0; off >>= 1) {
        v0 += __shfl_down(v0, off, 64);
        v1 += __shfl_down(v1, off, 64);
    }
    __shared__ float sRed[2][4];
    if (lane == 0) { sRed[0][wv] = v0; sRed[1][wv] = v1; }
    __syncthreads();
    if (threadIdx.x == 0) {
        out[b * 256 + i0] = q[b * 256 + i0] + (sRed[0][0] + sRed[0][1] + sRed[0][2] + sRed[0][3]);
        out[b * 256 + i1] = q[b * 256 + i1] + (sRed[1][0] + sRed[1][1] + sRed[1][2] + sRed[1][3]);
    }
}

extern "C" void kernel_launch(void* const* d_in, const int* in_sizes, int n_in,
                              void* d_out, int out_size, void* d_ws, size_t ws_size,
                              hipStream_t stream) {
    const float* h    = (const float*)d_in[0];
    const float* e    = (const float*)d_in[1];
    const float* x    = (const float*)d_in[2];
    const float* q    = (const float*)d_in[3];
    const float* mask = (const float*)d_in[4];
    const float* W1   = (const float*)d_in[5];
    const float* b1   = (const float*)d_in[6];
    const float* W2   = (const float*)d_in[7];
    const float* b2   = (const float*)d_in[8];
    const float* W3   = (const float*)d_in[9];
    float* out = (float*)d_out;
    float* AT  = (float*)d_ws;   // 2048*64 floats = 512 KB

    hipLaunchKernelGGL(precompute_kernel, dim3(512), dim3(256), 0, stream,
                       h, x, q, W1, AT);
    hipLaunchKernelGGL(edge_kernel, dim3(8 * 128), dim3(256), 0, stream,
                       e, q, mask, W1, b1, W2, b2, W3, AT, out);
}